// Round 4
// baseline (638.674 us; speedup 1.0000x reference)
//
#include <hip/hip_runtime.h>
#include <hip/hip_cooperative_groups.h>

namespace cg = cooperative_groups;

#define IMG_H 1024
#define IMG_W 1024
#define NBATCH 8
#define NCH 3
#define NPIX (IMG_H * IMG_W)
#define SEGS 64
#define NTOT (8388608LL)

#define BINS1 4096                      // level-1: bits >> 19
#define SH1 19

// ---- workspace layout (bytes) ----
#define WS_MISC_OFF   0                 // zeroed: lossAcc@0, gCnt[16]@64, sel1@128, resid1@256
#define WS_MISC_BYTES 4096
#define WS_H1R_OFF    (WS_MISC_OFF + WS_MISC_BYTES)
#define WS_H1R_BYTES  (2 * NBATCH * BINS1 * 4)         // 256 KB (zeroed: atomic targets)
#define WS_LISTC_OFF  (WS_H1R_OFF + WS_H1R_BYTES)      // coop path: list right after h1r
// fallback path keeps round-3 layout:
#define WS_H1P_OFF    (WS_H1R_OFF + WS_H1R_BYTES)
#define WS_H1P_BYTES  (2 * NBATCH * SEGS * BINS1 * 2)  // 8 MB
#define WS_LISTF_OFF  (WS_H1P_OFF + WS_H1P_BYTES)

struct Row3f { float l, c, r; };

__device__ __forceinline__ Row3f load3(const float* __restrict__ img, int y, int x) {
    Row3f o;
    if ((unsigned)y >= (unsigned)IMG_H) { o.l = o.c = o.r = 0.0f; return o; }
    const float* row = img + (size_t)y * IMG_W;
    o.c = row[x];
    o.l = (x > 0)         ? row[x - 1] : 0.0f;
    o.r = (x < IMG_W - 1) ? row[x + 1] : 0.0f;
    return o;
}

// BIT-EXACT vs reference: f32, row-major sequential tap order (verified rounds 2-3).
__device__ __forceinline__ float sobel_g(const Row3f& r0, const Row3f& r1, const Row3f& r2) {
    float gx = r0.r - r0.l;
    gx -= 2.0f * r1.l;
    gx += 2.0f * r1.r;
    gx -= r2.l;
    gx += r2.r;
    float gy = r0.l + 2.0f * r0.c;
    gy += r0.r;
    gy -= r2.l;
    gy -= 2.0f * r2.c;
    gy -= r2.r;
    return fabsf(gx) + fabsf(gy);
}

__device__ __forceinline__ unsigned read_k(const int* kptr) {
    long long kl = (long long)kptr[0];
    if (kl < 1 || kl > (long long)NPIX) {               // defensive: scalar sent as f32?
        float kf = ((const float*)kptr)[0];
        kl = (long long)kf;
        if (kl < 1) kl = 1;
        if (kl > NPIX) kl = NPIX;
    }
    return (unsigned)kl;
}

// =====================================================================
// Fused cooperative kernel: 256 blocks x 512 threads (1 block/CU).
// =====================================================================
union SharedU {
    struct { unsigned h[2 * BINS1]; double lsum[8]; } a;          // phase A: 32 KB + 64 B
    struct { uint2 bufA[1024], bufB[1024]; unsigned cnt[2], base[2]; } b; // phase B: 16.4 KB
    struct { unsigned h2[BINS1]; unsigned ls[512]; unsigned bc[4]; } c;   // phase S/C: 18.5 KB
};

extern "C" __global__ __launch_bounds__(512)
void k_fused(const float* __restrict__ A, const float* __restrict__ B,
             const float* __restrict__ F, const int* __restrict__ kptr,
             unsigned* __restrict__ hist1r, double* __restrict__ lossAcc,
             unsigned* __restrict__ gCnt, int* __restrict__ sel1, int* __restrict__ resid1,
             uint2* __restrict__ list, unsigned cap, float* __restrict__ out)
{
    __shared__ SharedU sh;
    cg::grid_group grid = cg::this_grid();
    const int t = threadIdx.x;
    const int blk = blockIdx.x;                         // 256 = 8 batches * 32 bands
    const int batch = blk >> 5;
    const int y0 = (blk & 31) * 32;

    const float* a = A + (size_t)batch * NCH * NPIX;    // channel 0
    const float* b = B + (size_t)batch * NCH * NPIX;
    const float* f = F + (size_t)batch * NCH * NPIX;

    // ---------------- phase A: hist + loss ----------------
    for (int i = t; i < 2 * BINS1; i += 512) sh.a.h[i] = 0u;
    __syncthreads();

    double loss = 0.0;
    for (int half = 0; half < 2; ++half) {
        const int x = half * 512 + t;
        Row3f a0 = load3(a, y0 - 1, x), a1 = load3(a, y0, x), a2;
        Row3f b0 = load3(b, y0 - 1, x), b1 = load3(b, y0, x), b2;
        Row3f f0 = load3(f, y0 - 1, x), f1 = load3(f, y0, x), f2;
        for (int i = 0; i < 32; ++i) {
            const int y = y0 + i;
            a2 = load3(a, y + 1, x);
            b2 = load3(b, y + 1, x);
            f2 = load3(f, y + 1, x);
            const float gA = sobel_g(a0, a1, a2);
            const float gB = sobel_g(b0, b1, b2);
            const float gF = sobel_g(f0, f1, f2);
            atomicAdd(&sh.a.h[__float_as_uint(gA) >> SH1], 1u);
            atomicAdd(&sh.a.h[BINS1 + (__float_as_uint(gB) >> SH1)], 1u);
            loss += (double)fabsf(gF - fmaxf(gA, gB));
            a0 = a1; a1 = a2;
            b0 = b1; b1 = b2;
            f0 = f1; f1 = f2;
        }
    }
    __syncthreads();

    // flush hist: only occupied bins (~100-200 of 8192) -> sparse global atomics
    for (int i = t; i < 2 * BINS1; i += 512) {
        const unsigned v = sh.a.h[i];
        if (v) {
            const int ib = (i < BINS1) ? batch : (NBATCH + batch);
            atomicAdd(&hist1r[(size_t)ib * BINS1 + (i & (BINS1 - 1))], v);
        }
    }
    for (int off = 32; off > 0; off >>= 1) loss += __shfl_down(loss, off);
    if ((t & 63) == 0) sh.a.lsum[t >> 6] = loss;
    __syncthreads();
    if (t == 0) {
        double s = 0.0;
        for (int i = 0; i < 8; ++i) s += sh.a.lsum[i];
        atomicAdd(lossAcc, s);
    }

    grid.sync();

    // ---------------- phase S: level-1 select (blocks 0..15) ----------------
    if (blk < 16) {
        const unsigned k = read_k(kptr);
        const uint4* hr4 = (const uint4*)(hist1r + (size_t)blk * BINS1);
        const uint4 ca = hr4[2 * t], cb = hr4[2 * t + 1];   // bins 8t..8t+7
        unsigned cc[8] = {ca.x, ca.y, ca.z, ca.w, cb.x, cb.y, cb.z, cb.w};
        unsigned s = 0;
        #pragma unroll
        for (int j = 0; j < 8; ++j) s += cc[j];
        sh.c.ls[t] = s; __syncthreads();
        for (int off = 1; off < 512; off <<= 1) {
            unsigned v = (t >= off) ? sh.c.ls[t - off] : 0u;
            __syncthreads();
            sh.c.ls[t] += v;
            __syncthreads();
        }
        const unsigned incl = sh.c.ls[t], excl = incl - s;
        if (excl < k && k <= incl) {                    // unique winner
            unsigned cum = excl, bin = 8u * t;
            #pragma unroll
            for (int j = 0; j < 8; ++j) {
                if (cum + cc[j] < k) { cum += cc[j]; ++bin; } else break;
            }
            sel1[blk] = (int)bin;
            resid1[blk] = (int)(k - cum);
        }
    }

    grid.sync();

    // ---------------- phase B: masks + candidate lists ----------------
    const unsigned sA = (unsigned)sel1[batch];
    const unsigned sB = (unsigned)sel1[NBATCH + batch];
    float* mA = out + 1 + (size_t)batch * NPIX;
    float* mB = out + 1 + (size_t)NTOT + (size_t)batch * NPIX;

    for (int half = 0; half < 2; ++half) {
        const int x = half * 512 + t;
        if (t == 0) { sh.b.cnt[0] = 0u; sh.b.cnt[1] = 0u; }
        __syncthreads();
        Row3f a0 = load3(a, y0 - 1, x), a1 = load3(a, y0, x), a2;
        Row3f b0 = load3(b, y0 - 1, x), b1 = load3(b, y0, x), b2;
        for (int i = 0; i < 32; ++i) {
            const int y = y0 + i;
            a2 = load3(a, y + 1, x);
            b2 = load3(b, y + 1, x);
            const unsigned uA = __float_as_uint(sobel_g(a0, a1, a2));
            const unsigned uB = __float_as_uint(sobel_g(b0, b1, b2));
            const unsigned binA = uA >> SH1, binB = uB >> SH1;
            const unsigned idx = (unsigned)y * IMG_W + (unsigned)x;
            mA[idx] = (binA > sA) ? 1.0f : 0.0f;        // boundary bin provisional 0, fixed in C
            mB[idx] = (binB > sB) ? 1.0f : 0.0f;
            if (binA == sA) { unsigned p = atomicAdd(&sh.b.cnt[0], 1u); if (p < 1024u) sh.b.bufA[p] = make_uint2(uA, idx); }
            if (binB == sB) { unsigned p = atomicAdd(&sh.b.cnt[1], 1u); if (p < 1024u) sh.b.bufB[p] = make_uint2(uB, idx); }
            a0 = a1; a1 = a2;
            b0 = b1; b1 = b2;

            if ((i & 1) == 1 || i == 31) {              // flush every 2 rows (max 1024/buf)
                __syncthreads();
                const unsigned nA = sh.b.cnt[0], nB = sh.b.cnt[1];
                if (nA | nB) {
                    if (t == 0) {
                        if (nA) sh.b.base[0] = atomicAdd(&gCnt[batch], nA);
                        if (nB) sh.b.base[1] = atomicAdd(&gCnt[NBATCH + batch], nB);
                    }
                    __syncthreads();
                    for (unsigned j = t; j < nA; j += 512u) {
                        const unsigned d = sh.b.base[0] + j;
                        if (d < cap) list[(size_t)batch * cap + d] = sh.b.bufA[j];
                    }
                    for (unsigned j = t; j < nB; j += 512u) {
                        const unsigned d = sh.b.base[1] + j;
                        if (d < cap) list[(size_t)(NBATCH + batch) * cap + d] = sh.b.bufB[j];
                    }
                    __syncthreads();
                    if (t == 0) { sh.b.cnt[0] = 0u; sh.b.cnt[1] = 0u; }
                }
                __syncthreads();
            }
        }
    }

    grid.sync();

    // ---------------- phase C: in-bin select + fix-up (blocks 0..15) ----------------
    if (blk < 16) {
        const int ib = blk;
        const unsigned n = min(gCnt[ib], cap);
        const unsigned kk = (unsigned)resid1[ib];
        const uint2* L = list + (size_t)ib * cap;

        if (t < 4) sh.c.bc[t] = 0u;
        for (int i = t; i < BINS1; i += 512) sh.c.h2[i] = 0u;
        __syncthreads();

        for (unsigned j = t; j < n; j += 512u) atomicAdd(&sh.c.h2[(L[j].x >> 7) & 4095u], 1u);
        __syncthreads();

        unsigned cc[8];
        unsigned s = 0;
        #pragma unroll
        for (int j = 0; j < 8; ++j) { cc[j] = sh.c.h2[8 * t + j]; s += cc[j]; }
        sh.c.ls[t] = s; __syncthreads();
        for (int off = 1; off < 512; off <<= 1) {
            unsigned v = (t >= off) ? sh.c.ls[t - off] : 0u;
            __syncthreads();
            sh.c.ls[t] += v;
            __syncthreads();
        }
        {
            const unsigned incl = sh.c.ls[t], excl = incl - s;
            if (excl < kk && kk <= incl) {
                unsigned cum = excl, bin = 8u * t;
                #pragma unroll
                for (int j = 0; j < 8; ++j) {
                    if (cum + cc[j] < kk) { cum += cc[j]; ++bin; } else break;
                }
                sh.c.bc[0] = bin;
                sh.c.bc[1] = kk - cum;
            }
        }
        __syncthreads();
        const unsigned sel2 = sh.c.bc[0], k3 = sh.c.bc[1];

        if (t < 128) sh.c.h2[t] = 0u;
        __syncthreads();
        for (unsigned j = t; j < n; j += 512u) {
            const unsigned bb = L[j].x;
            if (((bb >> 7) & 4095u) == sel2) atomicAdd(&sh.c.h2[bb & 127u], 1u);
        }
        __syncthreads();
        {
            const unsigned s3 = (t < 128) ? sh.c.h2[t] : 0u;
            sh.c.ls[t] = s3; __syncthreads();
            for (int off = 1; off < 512; off <<= 1) {
                unsigned v = (t >= off) ? sh.c.ls[t - off] : 0u;
                __syncthreads();
                sh.c.ls[t] += v;
                __syncthreads();
            }
            const unsigned incl = sh.c.ls[t], excl = incl - s3;
            if (t < 128 && excl < k3 && k3 <= incl)
                sh.c.bc[2] = ((unsigned)sel1[ib] << SH1) | (sel2 << 7) | (unsigned)t;
        }
        __syncthreads();
        const unsigned kth = sh.c.bc[2];

        float* m = out + 1 + (size_t)ib * NPIX;         // [A(0..7) | B(8..15)] contiguous
        for (unsigned j = t; j < n; j += 512u) {
            const uint2 e = L[j];
            m[e.y] = (e.x >= kth) ? 1.0f : 0.0f;
        }
        if (ib == 0 && t == 0) out[0] = (float)(lossAcc[0] * (1.0 / 8388608.0));
    }
}

// =====================================================================
// Fallback path: proven round-3 kernels (used only if coop launch fails)
// =====================================================================
extern "C" __global__ __launch_bounds__(512)
void k_pass0(const float* __restrict__ A, const float* __restrict__ B,
             const float* __restrict__ F,
             unsigned short* __restrict__ hist1p, double* __restrict__ lossAcc)
{
    __shared__ unsigned int h[4 * BINS1];
    __shared__ double lsum[8];
    const int t = threadIdx.x;
    for (int i = t; i < 4 * BINS1; i += 512) h[i] = 0u;
    __syncthreads();
    const int blk = blockIdx.x;
    const int batch = blk >> 6;
    const int seg = blk & 63;
    const int y0 = (seg >> 1) * 32;
    const int x  = (seg & 1) * 512 + t;
    unsigned int* hc = h + (t >> 8) * (2 * BINS1);
    const float* a = A + (size_t)batch * NCH * NPIX;
    const float* b = B + (size_t)batch * NCH * NPIX;
    const float* f = F + (size_t)batch * NCH * NPIX;
    Row3f a0 = load3(a, y0 - 1, x), a1 = load3(a, y0, x), a2;
    Row3f b0 = load3(b, y0 - 1, x), b1 = load3(b, y0, x), b2;
    Row3f f0 = load3(f, y0 - 1, x), f1 = load3(f, y0, x), f2;
    double loss = 0.0;
    for (int i = 0; i < 32; ++i) {
        const int y = y0 + i;
        a2 = load3(a, y + 1, x);
        b2 = load3(b, y + 1, x);
        f2 = load3(f, y + 1, x);
        const float gA = sobel_g(a0, a1, a2);
        const float gB = sobel_g(b0, b1, b2);
        const float gF = sobel_g(f0, f1, f2);
        atomicAdd(&hc[__float_as_uint(gA) >> SH1], 1u);
        atomicAdd(&hc[BINS1 + (__float_as_uint(gB) >> SH1)], 1u);
        loss += (double)fabsf(gF - fmaxf(gA, gB));
        a0 = a1; a1 = a2; b0 = b1; b1 = b2; f0 = f1; f1 = f2;
    }
    __syncthreads();
    unsigned short* oA = hist1p + ((size_t)batch            * SEGS + seg) * BINS1;
    unsigned short* oB = hist1p + ((size_t)(NBATCH + batch) * SEGS + seg) * BINS1;
    for (int i = t; i < 2 * BINS1; i += 512) {
        const unsigned v = h[i] + h[2 * BINS1 + i];
        if (i < BINS1) oA[i] = (unsigned short)v;
        else           oB[i - BINS1] = (unsigned short)v;
    }
    for (int off = 32; off > 0; off >>= 1) loss += __shfl_down(loss, off);
    if ((t & 63) == 0) lsum[t >> 6] = loss;
    __syncthreads();
    if (t == 0) {
        double s = 0.0;
        for (int i = 0; i < 8; ++i) s += lsum[i];
        atomicAdd(lossAcc, s);
    }
}

extern "C" __global__ __launch_bounds__(256)
void k_scan1a(const unsigned short* __restrict__ hist1p, unsigned int* __restrict__ hist1r)
{
    const int idx = blockIdx.x * 256 + threadIdx.x;
    const int ib  = idx >> 12;
    const int bin = idx & (BINS1 - 1);
    const unsigned short* p = hist1p + (size_t)ib * SEGS * BINS1 + bin;
    unsigned int s = 0;
    #pragma unroll 8
    for (int sg = 0; sg < SEGS; ++sg) s += p[(size_t)sg * BINS1];
    atomicAdd(&hist1r[idx], s);
}

extern "C" __global__ __launch_bounds__(1024)
void k_scan1b(const unsigned int* __restrict__ hist1r, const int* __restrict__ kptr,
              int* __restrict__ sel1, int* __restrict__ resid1)
{
    const int ib = blockIdx.x, t = threadIdx.x;
    const unsigned int* hr = hist1r + (size_t)ib * BINS1;
    const unsigned k = read_k(kptr);
    const uint4 c = ((const uint4*)hr)[t];
    const unsigned s = c.x + c.y + c.z + c.w;
    __shared__ unsigned ls[1024];
    ls[t] = s; __syncthreads();
    for (int off = 1; off < 1024; off <<= 1) {
        unsigned v = (t >= off) ? ls[t - off] : 0u;
        __syncthreads();
        ls[t] += v;
        __syncthreads();
    }
    const unsigned incl = ls[t], excl = incl - s;
    if (excl < k && k <= incl) {
        unsigned cum = excl; int bin = t * 4;
        if (cum + c.x < k) { cum += c.x; ++bin;
          if (cum + c.y < k) { cum += c.y; ++bin;
            if (cum + c.z < k) { cum += c.z; ++bin; } } }
        sel1[ib] = bin;
        resid1[ib] = (int)(k - cum);
    }
}

#define PB_ROWS 32
extern "C" __global__ __launch_bounds__(1024)
void k_passB(const float* __restrict__ A, const float* __restrict__ B,
             const int* __restrict__ sel1, unsigned int* __restrict__ gCnt,
             uint2* __restrict__ list, unsigned cap, float* __restrict__ out)
{
    const int t = threadIdx.x;
    const int blk = blockIdx.x;
    const int batch = blk >> 5;
    const int y0 = (blk & 31) * PB_ROWS;
    const int x = t;
    const float* a = A + (size_t)batch * NCH * NPIX;
    const float* b = B + (size_t)batch * NCH * NPIX;
    const unsigned sA = (unsigned)sel1[batch];
    const unsigned sB = (unsigned)sel1[NBATCH + batch];
    float* mA = out + 1 + (size_t)batch * NPIX;
    float* mB = out + 1 + (size_t)NTOT + (size_t)batch * NPIX;
    __shared__ uint2 bufA[2048], bufB[2048];
    __shared__ unsigned cntA, cntB, baseA, baseB;
    if (t == 0) { cntA = 0u; cntB = 0u; }
    __syncthreads();
    Row3f a0 = load3(a, y0 - 1, x), a1 = load3(a, y0, x), a2;
    Row3f b0 = load3(b, y0 - 1, x), b1 = load3(b, y0, x), b2;
    for (int i = 0; i < PB_ROWS; ++i) {
        const int y = y0 + i;
        a2 = load3(a, y + 1, x);
        b2 = load3(b, y + 1, x);
        const unsigned uA = __float_as_uint(sobel_g(a0, a1, a2));
        const unsigned uB = __float_as_uint(sobel_g(b0, b1, b2));
        const unsigned binA = uA >> SH1, binB = uB >> SH1;
        const unsigned idx = (unsigned)y * IMG_W + (unsigned)x;
        mA[idx] = (binA > sA) ? 1.0f : 0.0f;
        mB[idx] = (binB > sB) ? 1.0f : 0.0f;
        if (binA == sA) { unsigned p = atomicAdd(&cntA, 1u); bufA[p] = make_uint2(uA, idx); }
        if (binB == sB) { unsigned p = atomicAdd(&cntB, 1u); bufB[p] = make_uint2(uB, idx); }
        a0 = a1; a1 = a2; b0 = b1; b1 = b2;
        __syncthreads();
        const bool last = (i == PB_ROWS - 1);
        const unsigned nA = cntA, nB = cntB;
        const bool doA = (nA >= 1024u) || (last && nA > 0u);
        const bool doB = (nB >= 1024u) || (last && nB > 0u);
        if (doA || doB) {
            if (t == 0) {
                if (doA) baseA = atomicAdd(&gCnt[batch], nA);
                if (doB) baseB = atomicAdd(&gCnt[NBATCH + batch], nB);
            }
            __syncthreads();
            if (doA) for (unsigned j = t; j < nA; j += 1024u) {
                const unsigned d = baseA + j;
                if (d < cap) list[(size_t)batch * cap + d] = bufA[j];
            }
            if (doB) for (unsigned j = t; j < nB; j += 1024u) {
                const unsigned d = baseB + j;
                if (d < cap) list[(size_t)(NBATCH + batch) * cap + d] = bufB[j];
            }
            __syncthreads();
            if (t == 0) { if (doA) cntA = 0u; if (doB) cntB = 0u; }
        }
        __syncthreads();
    }
}

extern "C" __global__ __launch_bounds__(1024)
void k_selectfix(const uint2* __restrict__ list, const unsigned int* __restrict__ gCnt,
                 unsigned cap, const int* __restrict__ sel1, const int* __restrict__ resid1,
                 const double* __restrict__ lossAcc, float* __restrict__ out)
{
    const int ib = blockIdx.x, t = threadIdx.x;
    const unsigned n = min(gCnt[ib], cap);
    const unsigned kk = (unsigned)resid1[ib];
    const uint2* L = list + (size_t)ib * cap;
    __shared__ unsigned h2[BINS1];
    __shared__ unsigned ls[1024];
    __shared__ unsigned bcast[4];
    if (t < 4) bcast[t] = 0u;
    for (int i = t; i < BINS1; i += 1024) h2[i] = 0u;
    __syncthreads();
    for (unsigned j = t; j < n; j += 1024u) atomicAdd(&h2[(L[j].x >> 7) & 4095u], 1u);
    __syncthreads();
    const unsigned c0 = h2[4 * t], c1 = h2[4 * t + 1], c2 = h2[4 * t + 2], c3 = h2[4 * t + 3];
    const unsigned s = c0 + c1 + c2 + c3;
    ls[t] = s; __syncthreads();
    for (int off = 1; off < 1024; off <<= 1) {
        unsigned v = (t >= off) ? ls[t - off] : 0u;
        __syncthreads();
        ls[t] += v;
        __syncthreads();
    }
    {
        const unsigned incl = ls[t], excl = incl - s;
        if (excl < kk && kk <= incl) {
            unsigned cum = excl; unsigned bin = 4u * t;
            if (cum + c0 < kk) { cum += c0; ++bin;
              if (cum + c1 < kk) { cum += c1; ++bin;
                if (cum + c2 < kk) { cum += c2; ++bin; } } }
            bcast[0] = bin;
            bcast[1] = kk - cum;
        }
    }
    __syncthreads();
    const unsigned sel2 = bcast[0], k3 = bcast[1];
    if (t < 128) h2[t] = 0u;
    __syncthreads();
    for (unsigned j = t; j < n; j += 1024u) {
        const unsigned b = L[j].x;
        if (((b >> 7) & 4095u) == sel2) atomicAdd(&h2[b & 127u], 1u);
    }
    __syncthreads();
    {
        const unsigned s3 = (t < 128) ? h2[t] : 0u;
        ls[t] = s3; __syncthreads();
        for (int off = 1; off < 1024; off <<= 1) {
            unsigned v = (t >= off) ? ls[t - off] : 0u;
            __syncthreads();
            ls[t] += v;
            __syncthreads();
        }
        const unsigned incl = ls[t], excl = incl - s3;
        if (t < 128 && excl < k3 && k3 <= incl)
            bcast[2] = ((unsigned)sel1[ib] << SH1) | (sel2 << 7) | (unsigned)t;
    }
    __syncthreads();
    const unsigned kth = bcast[2];
    float* m = out + 1 + (size_t)ib * NPIX;
    for (unsigned j = t; j < n; j += 1024u) {
        const uint2 e = L[j];
        m[e.y] = (e.x >= kth) ? 1.0f : 0.0f;
    }
    if (ib == 0 && t == 0) out[0] = (float)(lossAcc[0] * (1.0 / 8388608.0));
}

extern "C" void kernel_launch(void* const* d_in, const int* in_sizes, int n_in,
                              void* d_out, int out_size, void* d_ws, size_t ws_size,
                              hipStream_t stream)
{
    const float* A = (const float*)d_in[0];
    const float* B = (const float*)d_in[1];
    const float* F = (const float*)d_in[2];
    const int* kptr = (const int*)d_in[3];
    float* out = (float*)d_out;

    if (ws_size < (size_t)WS_LISTF_OFF + 16 * 8 * 1024) return;

    char* ws = (char*)d_ws;
    double* lossAcc        = (double*)(ws + WS_MISC_OFF);
    unsigned int* gCnt     = (unsigned int*)(ws + WS_MISC_OFF + 64);
    int* sel1              = (int*)(ws + WS_MISC_OFF + 128);
    int* resid1            = (int*)(ws + WS_MISC_OFF + 256);
    unsigned int* hist1r   = (unsigned int*)(ws + WS_H1R_OFF);
    uint2* listC           = (uint2*)(ws + WS_LISTC_OFF);

    unsigned long long capCll = (ws_size - WS_LISTC_OFF) / (16ull * 8ull);
    unsigned capC = (capCll > (unsigned long long)NPIX) ? (unsigned)NPIX : (unsigned)capCll;

    // zero lossAcc/gCnt/sel/resid + hist1r (atomic targets) in one memset
    hipMemsetAsync(ws, 0, WS_MISC_BYTES + WS_H1R_BYTES, stream);

    void* kargs[] = {(void*)&A, (void*)&B, (void*)&F, (void*)&kptr,
                     (void*)&hist1r, (void*)&lossAcc, (void*)&gCnt,
                     (void*)&sel1, (void*)&resid1, (void*)&listC, (void*)&capC, (void*)&out};
    hipError_t e = hipLaunchCooperativeKernel((const void*)k_fused, dim3(256), dim3(512),
                                              kargs, 0, stream);
    if (e != hipSuccess) {
        // fallback: proven round-3 multi-dispatch path
        unsigned short* hist1p = (unsigned short*)(ws + WS_H1P_OFF);
        uint2* listF           = (uint2*)(ws + WS_LISTF_OFF);
        unsigned long long capFll = (ws_size - WS_LISTF_OFF) / (16ull * 8ull);
        unsigned capF = (capFll > (unsigned long long)NPIX) ? (unsigned)NPIX : (unsigned)capFll;
        k_pass0    <<<dim3(NBATCH * SEGS), dim3(512), 0, stream>>>(A, B, F, hist1p, lossAcc);
        k_scan1a   <<<dim3(2 * NBATCH * BINS1 / 256), dim3(256), 0, stream>>>(hist1p, hist1r);
        k_scan1b   <<<dim3(2 * NBATCH), dim3(1024), 0, stream>>>(hist1r, kptr, sel1, resid1);
        k_passB    <<<dim3(NBATCH * 32), dim3(1024), 0, stream>>>(A, B, sel1, gCnt, listF, capF, out);
        k_selectfix<<<dim3(2 * NBATCH), dim3(1024), 0, stream>>>(listF, gCnt, capF, sel1, resid1, lossAcc, out);
    }
}